// Round 5
// baseline (1156.464 us; speedup 1.0000x reference)
//
#include <hip/hip_runtime.h>
#include <hip/hip_bf16.h>
#include <cstdint>
#include <cstddef>

typedef __hip_bfloat16 bf16;
typedef __attribute__((ext_vector_type(8))) short short8;
typedef __attribute__((ext_vector_type(4))) float floatx4;

__device__ __forceinline__ void gload_lds16(const void* g, void* l) {
  __builtin_amdgcn_global_load_lds(
      (__attribute__((address_space(1))) void*)(uintptr_t)g,
      (__attribute__((address_space(3))) void*)l, 16, 0, 0);
}

__device__ __forceinline__ short f2bbits(float f) {
  bf16 h = __float2bfloat16(f);
  return __builtin_bit_cast(short, h);
}
__device__ __forceinline__ float b2f(short s) {
  return __bfloat162float(__builtin_bit_cast(bf16, s));
}

// ---------------- x (fp32) -> xb (bf16), 8 elems/thread ----------------
__global__ __launch_bounds__(256) void convert_x(const float* __restrict__ x,
                                                 bf16* __restrict__ xb) {
  size_t i = ((size_t)blockIdx.x * 256 + threadIdx.x) * 8;
  float4 f0 = *(const float4*)(x + i);
  float4 f1 = *(const float4*)(x + i + 4);
  short8 r;
  r[0] = f2bbits(f0.x); r[1] = f2bbits(f0.y); r[2] = f2bbits(f0.z); r[3] = f2bbits(f0.w);
  r[4] = f2bbits(f1.x); r[5] = f2bbits(f1.y); r[6] = f2bbits(f1.z); r[7] = f2bbits(f1.w);
  *(short8*)(xb + i) = r;
}

// -------- W (1024 x cols, row-major fp32) -> dst[n][k] bf16 (transposed) --------
__global__ __launch_bounds__(256) void transpose_w(const float* __restrict__ src,
                                                   bf16* __restrict__ dst, int cols) {
  __shared__ float tile[32][33];
  int n0 = blockIdx.x * 32, k0 = blockIdx.y * 32;
  int tx = threadIdx.x & 31, ty = threadIdx.x >> 5;
#pragma unroll
  for (int i = 0; i < 32; i += 8) {
    int kk = k0 + ty + i, nn = n0 + tx;
    tile[ty + i][tx] = (nn < cols) ? src[(size_t)kk * cols + nn] : 0.0f;
  }
  __syncthreads();
#pragma unroll
  for (int i = 0; i < 32; i += 8) {
    int nn = n0 + ty + i, kk = k0 + tx;
    if (nn < cols) dst[(size_t)nn * 1024 + kk] = __float2bfloat16(tile[tx][ty + i]);
  }
}

// =====================================================================
// 256x256-tile bf16 MFMA GEMM, 8-wave (2Mx4N), BK=64.
// v5 = v4 with the K-coverage bug fixed: 16 iterations x 1 K-tile (64)
// per iteration = K 1024 (v4 ran 8 iters = K 512 -> absmax 3.47).
// Register-double-buffered pipeline, 1 barrier/phase (4+1 per K-tile).
// Next tile's A0/B0/B1 frags issue at end of p4 (overlap MFMA drain);
// A1 issues in p2. No manual lgkm waits (compiler derives counted waits).
// vmcnt ledger: WAITV(4) at each tile's p4 retires exactly tile t+1.
// T2 XOR-swizzle LDS, T5 setprio, T1 XCD-bijective block swizzle.
// mode 0: projection epilogue, N=3072 (512 q | 512 k | 1024 v | 1024 g).
// mode 1: fp32 out, N=1024. K fixed = 1024.
// =====================================================================
#define BARR __builtin_amdgcn_s_barrier()
#define WAITV(n) asm volatile("s_waitcnt vmcnt(" #n ")" ::: "memory")

#define KC 1024
#define K64c (KC * 64)
#define K128c (KC * 128)
#define K32c (KC * 32)

// LDS map (shorts): A: buf*16384 + half*8192 ; B: 32768 + buf*16384 + half*8192
// Swizzle: 16B-granule p_phys = p_logical ^ (physrow & 7).
#define STA(buf, h, tau) do { \
  gload_lds16(pA + (size_t)((h) * K64c + (tau) * 64), \
              &lds[(buf) * 16384 + (h) * 8192 + w * 512]); \
  gload_lds16(pA + (size_t)(K128c + (h) * K64c + (tau) * 64), \
              &lds[(buf) * 16384 + (h) * 8192 + 4096 + w * 512]); \
} while (0)

#define STB(buf, h, tau) do { \
  gload_lds16(pB + (size_t)((h) * K32c + (tau) * 64), \
              &lds[32768 + (buf) * 16384 + (h) * 8192 + w * 512]); \
  gload_lds16(pB + (size_t)(K128c + (h) * K32c + (tau) * 64), \
              &lds[32768 + (buf) * 16384 + (h) * 8192 + 4096 + w * 512]); \
} while (0)

#define LDA2(mh, buf, AR) do { \
  _Pragma("unroll") \
  for (int mp = 0; mp < 4; ++mp) { \
    const short* p_ = &lds[(buf) * 16384 + (mh) * 8192 + aRow + mp * 1024]; \
    AR[mp][0] = *(const short8*)(p_ + g0); \
    AR[mp][1] = *(const short8*)(p_ + g1); \
  } \
} while (0)

#define LDB(nh, buf, d0, d1) do { \
  const short* p_ = &lds[(buf) * 16384 + (nh) * 8192 + bRow]; \
  d0[0] = *(const short8*)(p_ + g0); \
  d0[1] = *(const short8*)(p_ + g1); \
  d1[0] = *(const short8*)(p_ + 1024 + g0); \
  d1[1] = *(const short8*)(p_ + 1024 + g1); \
} while (0)

#define MQ(MB, NB, AR, d0, d1) do { \
  __builtin_amdgcn_s_setprio(1); \
  _Pragma("unroll") \
  for (int mp = 0; mp < 4; ++mp) { \
    acc[(MB) + mp][(NB)] = __builtin_amdgcn_mfma_f32_16x16x32_bf16(AR[mp][0], d0[0], acc[(MB) + mp][(NB)], 0, 0, 0); \
    acc[(MB) + mp][(NB)] = __builtin_amdgcn_mfma_f32_16x16x32_bf16(AR[mp][1], d0[1], acc[(MB) + mp][(NB)], 0, 0, 0); \
    acc[(MB) + mp][(NB) + 1] = __builtin_amdgcn_mfma_f32_16x16x32_bf16(AR[mp][0], d1[0], acc[(MB) + mp][(NB) + 1], 0, 0, 0); \
    acc[(MB) + mp][(NB) + 1] = __builtin_amdgcn_mfma_f32_16x16x32_bf16(AR[mp][1], d1[1], acc[(MB) + mp][(NB) + 1], 0, 0, 0); \
  } \
  __builtin_amdgcn_s_setprio(0); \
} while (0)

__global__ __launch_bounds__(512, 2) void gemm256(
    const bf16* __restrict__ A, const bf16* __restrict__ Bt,
    const int nTN, const int mode,
    float* __restrict__ oq, float* __restrict__ okk, bf16* __restrict__ ov,
    bf16* __restrict__ ogg, float* __restrict__ oo) {
  extern __shared__ __align__(16) short lds[];
  const int tid = threadIdx.x;
  const int w = tid >> 6, lane = tid & 63;
  const int wr = w >> 2, wc = w & 3;               // 2M x 4N waves
  const int l15 = lane & 15, lq = lane >> 4;
  const int e7 = lane & 7, l3 = lane >> 3;
  const int gAp = (lane & 7) ^ l3;                 // staging: inverse-swizzled src granule

  // T1: bijective XCD swizzle (grid % 8 == 0), n-tile fastest for A reuse.
  const int cpx = (int)gridDim.x >> 3;
  const int bid = blockIdx.x;
  const int swz = (bid & 7) * cpx + (bid >> 3);
  const int mt = swz / nTN, nt = swz - mt * nTN;
  const int m0 = mt << 8, n0 = nt << 8;

  const bf16* pA = A + (size_t)(m0 + w * 8 + l3) * KC + gAp * 8;
  const bf16* pB = Bt + (size_t)(n0 + (w >> 2) * 64 + (w & 3) * 8 + l3) * KC + gAp * 8;

  const int g0 = ((lq ^ e7) & 7) * 8;              // kk=0 swizzled granule (shorts)
  const int g1 = (((lq + 4) ^ e7) & 7) * 8;        // kk=1
  const int aRow = (wr * 64 + l15) * 64;
  const int bRow = 32768 + (wc * 32 + l15) * 64;

  floatx4 acc[8][4] = {};
  short8 aA[4][2], aB[4][2], p0a[2], p0b[2], p1a[2], p1b[2];

  // Prologue: tile0 all 4 halves (8 loads, oldest), tile1 A-h0 + B-h1 (4 loads).
  STA(0, 0, 0); STA(0, 1, 0); STB(0, 0, 0); STB(0, 1, 0);
  STA(1, 0, 1); STB(1, 1, 1);
  WAITV(4);          // tile0 resident; 4 in flight (tile1's first halves)
  BARR;
  LDA2(0, 0, aA); LDB(0, 0, p0a, p0b); LDB(1, 0, p1a, p1b);

#pragma unroll 2
  for (int t = 0; t < 16; ++t) {       // 16 K-tiles of 64 = K 1024
    const int c = t & 1;
    // ---- p1: MFMA(M0,N0); stage A-h1 of t+1 ----
    if (t < 15) STA(c ^ 1, 1, t + 1);
    MQ(0, 0, aA, p0a, p0b);            // compiler waits lgkm for aA,p0*
    BARR;
    // ---- p2: issue A1 reads; stage B-h0 of t+1; MFMA(M0,N1) ----
    LDA2(1, c, aB);
    if (t < 15) STB(c ^ 1, 0, t + 1);
    MQ(0, 2, aA, p1a, p1b);            // lgkm: p1* done, aB in flight
    BARR;
    // ---- p3: stage A-h0 of t+2; MFMA(M1,N1) ----
    if (t < 14) STA(c, 0, t + 2);
    MQ(4, 2, aB, p1a, p1b);            // lgkm(0): aB done
    BARR;
    // ---- p4: stage B-h1 of t+2; MFMA(M1,N0); tile boundary; next-tile reads ----
    if (t < 14) STB(c, 1, t + 2);
    MQ(4, 0, aB, p0a, p0b);            // no wait (all operands resident)
    if (t < 14) { WAITV(4); }
    else if (t == 14) { WAITV(0); }
    if (t < 15) {
      BARR;                            // cross-wave: tile t+1 buf resident
      LDA2(0, c ^ 1, aA); LDB(0, c ^ 1, p0a, p0b); LDB(1, c ^ 1, p1a, p1b);
    }
  }

  // Epilogue: C row = m0 + wr*128 + m*16 + lq*4 + r ; col = n0 + wc*64 + n*16 + l15
  const int rq = lq * 4;
#pragma unroll
  for (int m = 0; m < 8; ++m) {
#pragma unroll
    for (int n = 0; n < 4; ++n) {
      const int col = n0 + wc * 64 + n * 16 + l15;
#pragma unroll
      for (int r = 0; r < 4; ++r) {
        const size_t row = (size_t)(m0 + wr * 128 + m * 16 + rq + r);
        const float val = acc[m][n][r];
        if (mode == 1) {
          oo[row * 1024 + col] = val;
        } else if (col < 512) {
          oq[row * 512 + col] = val * 0.08838834764831845f;
        } else if (col < 1024) {
          okk[row * 512 + (col - 512)] = val;
        } else if (col < 2048) {
          ov[row * 1024 + (col - 1024)] = __float2bfloat16(val);
        } else {
          ogg[row * 1024 + (col - 2048)] = __float2bfloat16(val);
        }
      }
    }
  }
}

// ------------- gk = log_sigmoid((x @ w1) @ w2 + b2) / 16, log-space out -------------
// 4 rows per block; w1/w2 slices held in registers (fully static indexing).
__global__ __launch_bounds__(256) void gate_decay2(const float* __restrict__ x,
                                                   const float* __restrict__ w1,
                                                   const float* __restrict__ w2,
                                                   const float* __restrict__ b2,
                                                   float* __restrict__ gkout) {
  __shared__ float sp[256];
  __shared__ float sz[16];
  const int m0 = blockIdx.x * 4, tid = threadIdx.x;
  const int j = tid & 15, dpart = tid >> 4;
  float w1r[64];
#pragma unroll
  for (int e = 0; e < 64; ++e) w1r[e] = w1[(dpart * 64 + e) * 16 + j];
  float w2r[32];
#pragma unroll
  for (int jj = 0; jj < 16; ++jj) {
    w2r[jj] = w2[jj * 512 + tid];
    w2r[16 + jj] = w2[jj * 512 + tid + 256];
  }
  const float b2a = b2[tid], b2b = b2[tid + 256];
  for (int r = 0; r < 4; ++r) {
    const int m = m0 + r;
    const float* xr = x + (size_t)m * 1024 + dpart * 64;
    float acc = 0.f;
#pragma unroll
    for (int e = 0; e < 64; ++e) acc = fmaf(xr[e], w1r[e], acc);
    sp[tid] = acc;
    __syncthreads();
    if (tid < 16) {
      float s = 0.f;
#pragma unroll
      for (int p = 0; p < 16; ++p) s += sp[p * 16 + tid];
      sz[tid] = s;
    }
    __syncthreads();
    float t = b2a;
#pragma unroll
    for (int jj = 0; jj < 16; ++jj) t = fmaf(sz[jj], w2r[jj], t);
    const float ls = fminf(t, 0.f) - log1pf(__expf(-fabsf(t)));
    gkout[(size_t)m * 512 + tid] = ls * 0.0625f;
    float t2 = b2b;
#pragma unroll
    for (int jj = 0; jj < 16; ++jj) t2 = fmaf(sz[jj], w2r[16 + jj], t2);
    const float ls2 = fminf(t2, 0.f) - log1pf(__expf(-fabsf(t2)));
    gkout[(size_t)m * 512 + tid + 256] = ls2 * 0.0625f;
    if (r < 3) __syncthreads();
  }
}

// ------------- chunk prep: b=cumsum(gk); Qt=q*e^b, Kt=k*e^-b, Dtot=e^Btot -------------
__global__ __launch_bounds__(128) void chunk_prep(
    const float* __restrict__ q, const float* __restrict__ k,
    const float* __restrict__ gk, bf16* __restrict__ qt,
    bf16* __restrict__ kt, float* __restrict__ dtot) {
  const int cid = blockIdx.x;
  const int c = cid & 63, h = (cid >> 6) & 3, b = cid >> 8;
  const int d = threadIdx.x;
  const size_t rowbase = ((size_t)(b * 4096 + c * 64)) * 512 + h * 128 + d;
  const size_t obase = (size_t)cid * 8192 + d;
  float bsum = 0.f;
  for (int i = 0; i < 64; ++i) {
    const size_t src = rowbase + (size_t)i * 512;
    bsum += gk[src];
    qt[obase + (size_t)i * 128] = __float2bfloat16(q[src] * __expf(bsum));
    kt[obase + (size_t)i * 128] = __float2bfloat16(k[src] * __expf(-bsum));
  }
  dtot[cid * 128 + d] = __expf(bsum);
}

// ------------- chunk intra: A=tril(Qt@Kt^T); o_intra=A@V; U^T=V^T@(Kt*Dtot) -------------
__global__ __launch_bounds__(256) void chunk_intra(
    const bf16* __restrict__ qt, const bf16* __restrict__ kt,
    const float* __restrict__ dtot, const bf16* __restrict__ v,
    bf16* __restrict__ oi, bf16* __restrict__ ut) {
  __shared__ __align__(16) short lA[64 * 72];
  __shared__ __align__(16) short stg[27648];
  short* sQ = stg;               // 64 x 136
  short* sK = stg + 8704;        // 64 x 136
  short* sVT = stg;              // 256 x 72
  short* sKhT = stg + 18432;     // 128 x 72
  const int cid = blockIdx.x;
  const int c = cid & 63, h = (cid >> 6) & 3, b = cid >> 8;
  const int tid = threadIdx.x, wv = tid >> 6, lane = tid & 63;
  const int l15 = lane & 15, q8 = (lane >> 4) * 8, rq = (lane >> 4) * 4;

  {
    const int row = tid >> 2, seg = (tid & 3) * 32;
    const size_t src = (size_t)cid * 8192 + row * 128 + seg;
    const short8* qs = (const short8*)(qt + src);
    const short8* ks = (const short8*)(kt + src);
    short8* qd = (short8*)&sQ[row * 136 + seg];
    short8* kd = (short8*)&sK[row * 136 + seg];
#pragma unroll
    for (int t = 0; t < 4; ++t) { qd[t] = qs[t]; kd[t] = ks[t]; }
  }
  __syncthreads();
  {
    short8 af[4];
#pragma unroll
    for (int kf = 0; kf < 4; ++kf)
      af[kf] = *(const short8*)&sQ[(wv * 16 + l15) * 136 + kf * 32 + q8];
#pragma unroll
    for (int nt = 0; nt < 4; ++nt) {
      floatx4 accA = {0.f, 0.f, 0.f, 0.f};
#pragma unroll
      for (int kf = 0; kf < 4; ++kf) {
        short8 bfr = *(const short8*)&sK[(nt * 16 + l15) * 136 + kf * 32 + q8];
        accA = __builtin_amdgcn_mfma_f32_16x16x32_bf16(af[kf], bfr, accA, 0, 0, 0);
      }
#pragma unroll
      for (int r = 0; r < 4; ++r) {
        const int i = wv * 16 + rq + r, jj = nt * 16 + l15;
        lA[i * 72 + jj] = f2bbits(jj <= i ? accA[r] : 0.f);
      }
    }
  }
  __syncthreads();
  {
#pragma unroll
    for (int e = 0; e < 8; ++e) {
      const int idx = tid + e * 256;
      const int jj = idx >> 5, n0 = (idx & 31) * 8;
      short8 vv = *(const short8*)(v + ((size_t)(b * 4096 + c * 64 + jj)) * 1024 + h * 256 + n0);
#pragma unroll
      for (int t = 0; t < 8; ++t) sVT[(n0 + t) * 72 + jj] = vv[t];
    }
#pragma unroll
    for (int e = 0; e < 4; ++e) {
      const int idx = tid + e * 256;
      const int jj = idx >> 4, d0 = (idx & 15) * 8;
      short8 kk = *(const short8*)(kt + (size_t)cid * 8192 + jj * 128 + d0);
#pragma unroll
      for (int t = 0; t < 8; ++t)
        sKhT[(d0 + t) * 72 + jj] = f2bbits(b2f(kk[t]) * dtot[cid * 128 + d0 + t]);
    }
  }
  __syncthreads();
  {
    short8 aA0 = *(const short8*)&lA[(wv * 16 + l15) * 72 + q8];
    short8 aA1 = *(const short8*)&lA[(wv * 16 + l15) * 72 + 32 + q8];
#pragma unroll
    for (int nt = 0; nt < 16; ++nt) {
      short8 b0 = *(const short8*)&sVT[(nt * 16 + l15) * 72 + q8];
      short8 b1 = *(const short8*)&sVT[(nt * 16 + l15) * 72 + 32 + q8];
      floatx4 acc = {0.f, 0.f, 0.f, 0.f};
      acc = __builtin_amdgcn_mfma_f32_16x16x32_bf16(aA0, b0, acc, 0, 0, 0);
      acc = __builtin_amdgcn_mfma_f32_16x16x32_bf16(aA1, b1, acc, 0, 0, 0);
#pragma unroll
      for (int r = 0; r < 4; ++r) {
        const int i = wv * 16 + rq + r;
        oi[(size_t)cid * 16384 + i * 256 + nt * 16 + l15] = __builtin_bit_cast(bf16, f2bbits(acc[r]));
      }
    }
  }
  {
    short8 aV[4][2];
#pragma unroll
    for (int mt = 0; mt < 4; ++mt) {
      aV[mt][0] = *(const short8*)&sVT[(wv * 64 + mt * 16 + l15) * 72 + q8];
      aV[mt][1] = *(const short8*)&sVT[(wv * 64 + mt * 16 + l15) * 72 + 32 + q8];
    }
#pragma unroll
    for (int nt = 0; nt < 8; ++nt) {
      short8 b0 = *(const short8*)&sKhT[(nt * 16 + l15) * 72 + q8];
      short8 b1 = *(const short8*)&sKhT[(nt * 16 + l15) * 72 + 32 + q8];
#pragma unroll
      for (int mt = 0; mt < 4; ++mt) {
        floatx4 acc = {0.f, 0.f, 0.f, 0.f};
        acc = __builtin_amdgcn_mfma_f32_16x16x32_bf16(aV[mt][0], b0, acc, 0, 0, 0);
        acc = __builtin_amdgcn_mfma_f32_16x16x32_bf16(aV[mt][1], b1, acc, 0, 0, 0);
#pragma unroll
        for (int r = 0; r < 4; ++r) {
          const int vr = wv * 64 + mt * 16 + rq + r;
          ut[(size_t)cid * 32768 + vr * 128 + nt * 16 + l15] = __builtin_bit_cast(bf16, f2bbits(acc[r]));
        }
      }
    }
  }
}

// ------------- state propagation, IN PLACE over ut -------------
// 512 blocks (2/CU), 8 fp32 states per thread for latency hiding.
__global__ __launch_bounds__(256) void state_prop(
    bf16* __restrict__ su,          // in: U^T per chunk; out: S_pre per chunk
    const float* __restrict__ dtot) {
  const int ng = blockIdx.x, h = blockIdx.y, b = blockIdx.z;
  const int tid = threadIdx.x;
  const int nrow = ng * 16 + (tid >> 4), kseg = (tid & 15) * 8;
  const int cid0 = (b * 4 + h) * 64;
  size_t a = (size_t)cid0 * 32768 + (size_t)nrow * 128 + kseg;
  float S[8];
#pragma unroll
  for (int e = 0; e < 8; ++e) S[e] = 0.f;
  short8 u0 = *(const short8*)(su + a);
  for (int c = 0; c < 64; ++c) {
    short8 un0;
    if (c < 63) un0 = *(const short8*)(su + a + 32768);
    const float4 d0 = *(const float4*)(dtot + (cid0 + c) * 128 + kseg);
    const float4 d1 = *(const float4*)(dtot + (cid0 + c) * 128 + kseg + 4);
    short8 s0;
#pragma unroll
    for (int e = 0; e < 8; ++e) s0[e] = f2bbits(S[e]);
    *(short8*)(su + a) = s0;       // write S_pre over consumed U
    const float dd[8] = {d0.x, d0.y, d0.z, d0.w, d1.x, d1.y, d1.z, d1.w};
#pragma unroll
    for (int e = 0; e < 8; ++e) S[e] = fmaf(dd[e], S[e], b2f(u0[e]));
    u0 = un0;
    a += 32768;
  }
}

// ------------- o_inter: opre = oi + Qt @ S_pre  (per chunk, MFMA) -------------
__global__ __launch_bounds__(256, 2) void o_inter(
    const bf16* __restrict__ qt, const bf16* __restrict__ scb,
    const bf16* __restrict__ oi, bf16* __restrict__ opre) {
  __shared__ __align__(16) short sQ[64 * 136];
  const int cid = blockIdx.x;
  const int c = cid & 63, h = (cid >> 6) & 3, b = cid >> 8;
  const int tid = threadIdx.x, wv = tid >> 6, lane = tid & 63;
  const int l15 = lane & 15, q8 = (lane >> 4) * 8, rq = (lane >> 4) * 4;
  {
    const int row = tid >> 2, seg = (tid & 3) * 32;
    const short8* qs = (const short8*)(qt + (size_t)cid * 8192 + row * 128 + seg);
    short8* qd = (short8*)&sQ[row * 136 + seg];
#pragma unroll
    for (int t = 0; t < 4; ++t) qd[t] = qs[t];
  }
  __syncthreads();
  short8 af[4][4];
#pragma unroll
  for (int i = 0; i < 4; ++i)
#pragma unroll
    for (int kf = 0; kf < 4; ++kf)
      af[i][kf] = *(const short8*)&sQ[(i * 16 + l15) * 136 + kf * 32 + q8];
  floatx4 acc[4][4] = {};
#pragma unroll
  for (int j = 0; j < 4; ++j) {
#pragma unroll
    for (int kf = 0; kf < 4; ++kf) {
      short8 bfr = *(const short8*)(scb + (size_t)cid * 32768 +
                                    (size_t)(wv * 64 + j * 16 + l15) * 128 + kf * 32 + q8);
#pragma unroll
      for (int i = 0; i < 4; ++i)
        acc[i][j] = __builtin_amdgcn_mfma_f32_16x16x32_bf16(af[i][kf], bfr, acc[i][j], 0, 0, 0);
    }
  }
  const size_t rowg0 = (size_t)(b * 4096 + c * 64);
#pragma unroll
  for (int i = 0; i < 4; ++i) {
#pragma unroll
    for (int j = 0; j < 4; ++j) {
      const int col = wv * 64 + j * 16 + l15;
#pragma unroll
      for (int r = 0; r < 4; ++r) {
        const int row = i * 16 + rq + r;
        const float val = acc[i][j][r] +
            __bfloat162float(oi[(size_t)cid * 16384 + row * 256 + col]);
        opre[(rowg0 + row) * 1024 + h * 256 + col] = __float2bfloat16(val);
      }
    }
  }
}

// ---------------- per-head RMSNorm * g_norm_w, then * swish(g) ----------------
__global__ __launch_bounds__(1024) void norm_gate(
    const bf16* __restrict__ o, const bf16* __restrict__ g,
    const float* __restrict__ gnw, bf16* __restrict__ og) {
  __shared__ float sp[16];
  const int tid = threadIdx.x;
  const size_t idx = (size_t)blockIdx.x * 1024 + tid;
  const float f = __bfloat162float(o[idx]);
  float ss = f * f;
#pragma unroll
  for (int mm = 1; mm <= 32; mm <<= 1) ss += __shfl_xor(ss, mm);
  if ((tid & 63) == 0) sp[tid >> 6] = ss;
  __syncthreads();
  const int h4 = (tid >> 8) * 4;
  const float ms = (sp[h4] + sp[h4 + 1] + sp[h4 + 2] + sp[h4 + 3]) * (1.0f / 256.0f);
  const float scale = rsqrtf(ms + 1e-5f) * gnw[tid & 255];
  const float gv = __bfloat162float(g[idx]);
  const float sw = gv * (1.0f / (1.0f + __expf(-gv)));
  og[idx] = __float2bfloat16(f * scale * sw);
}

extern "C" void kernel_launch(void* const* d_in, const int* in_sizes, int n_in,
                              void* d_out, int out_size, void* d_ws, size_t ws_size,
                              hipStream_t stream) {
  const float* x   = (const float*)d_in[0];
  const float* Wq  = (const float*)d_in[1];
  const float* Wk  = (const float*)d_in[2];
  const float* Wv  = (const float*)d_in[3];
  const float* gw1 = (const float*)d_in[4];
  const float* gw2 = (const float*)d_in[5];
  const float* gb2 = (const float*)d_in[6];
  const float* Wg  = (const float*)d_in[7];
  const float* gnw = (const float*)d_in[8];
  const float* Wo  = (const float*)d_in[9];
  float* out = (float*)d_out;

  static bool attr_set = false;
  if (!attr_set) {
    hipFuncSetAttribute(reinterpret_cast<const void*>(gemm256),
                        hipFuncAttributeMaxDynamicSharedMemorySize, 131072);
    attr_set = true;
  }

  // carve unchanged (393 MiB); scb == utb (in-place state_prop).
  const size_t Mi = 1048576;
  uint8_t* w = (uint8_t*)d_ws;
  bf16*  wallT = (bf16*)(w);
  bf16*  woT   = (bf16*)(w + 6 * Mi);
  float* dtot  = (float*)(w + 8 * Mi);
  bf16*  xb    = (bf16*)(w + 9 * Mi);
  bf16*  qt    = (bf16*)(w + 9 * Mi);
  bf16*  ktb   = (bf16*)(w + 41 * Mi);
  bf16*  ogat  = (bf16*)(w + 9 * Mi);
  float* qb    = (float*)(w + 73 * Mi);
  float* kb    = (float*)(w + 137 * Mi);
  bf16*  utb   = (bf16*)(w + 73 * Mi);    // U^T then S_pre (in place)
  float* gkb   = (float*)(w + 201 * Mi);
  bf16*  oib   = (bf16*)(w + 201 * Mi);
  bf16*  vb    = (bf16*)(w + 265 * Mi);
  bf16*  opre  = (bf16*)(w + 265 * Mi);
  bf16*  gb    = (bf16*)(w + 329 * Mi);

  convert_x<<<dim3(16384), 256, 0, stream>>>(x, xb);
  transpose_w<<<dim3(16, 32), 256, 0, stream>>>(Wq, wallT, 512);
  transpose_w<<<dim3(16, 32), 256, 0, stream>>>(Wk, wallT + (size_t)512 * 1024, 512);
  transpose_w<<<dim3(32, 32), 256, 0, stream>>>(Wv, wallT + (size_t)1024 * 1024, 1024);
  transpose_w<<<dim3(32, 32), 256, 0, stream>>>(Wg, wallT + (size_t)2048 * 1024, 1024);
  transpose_w<<<dim3(32, 32), 256, 0, stream>>>(Wo, woT, 1024);
  gemm256<<<dim3(1536), 512, 131072, stream>>>(xb, wallT, 12, 0, qb, kb, vb, gb, nullptr);
  gate_decay2<<<dim3(8192), 256, 0, stream>>>(x, gw1, gw2, gb2, gkb);
  chunk_prep<<<dim3(2048), 128, 0, stream>>>(qb, kb, gkb, qt, ktb, dtot);
  chunk_intra<<<dim3(2048), 256, 0, stream>>>(qt, ktb, dtot, vb, oib, utb);
  state_prop<<<dim3(16, 4, 8), 256, 0, stream>>>(utb, dtot);
  o_inter<<<dim3(2048), 256, 0, stream>>>(qt, utb, oib, opre);
  norm_gate<<<dim3(32768), 1024, 0, stream>>>(opre, gb, gnw, ogat);
  gemm256<<<dim3(512), 512, 131072, stream>>>(ogat, woT, 4, 1, nullptr, nullptr, nullptr, nullptr, out);
}

// Round 6
// 1014.763 us; speedup vs baseline: 1.1396x; 1.1396x over previous
//
#include <hip/hip_runtime.h>
#include <hip/hip_bf16.h>
#include <cstdint>
#include <cstddef>

typedef __hip_bfloat16 bf16;
typedef __attribute__((ext_vector_type(8))) short short8;
typedef __attribute__((ext_vector_type(4))) float floatx4;

__device__ __forceinline__ void gload_lds16(const void* g, void* l) {
  __builtin_amdgcn_global_load_lds(
      (__attribute__((address_space(1))) void*)(uintptr_t)g,
      (__attribute__((address_space(3))) void*)l, 16, 0, 0);
}

__device__ __forceinline__ short f2bbits(float f) {
  bf16 h = __float2bfloat16(f);
  return __builtin_bit_cast(short, h);
}
__device__ __forceinline__ float b2f(short s) {
  return __bfloat162float(__builtin_bit_cast(bf16, s));
}

// ---------------- x (fp32) -> xb (bf16), 8 elems/thread ----------------
__global__ __launch_bounds__(256) void convert_x(const float* __restrict__ x,
                                                 bf16* __restrict__ xb) {
  size_t i = ((size_t)blockIdx.x * 256 + threadIdx.x) * 8;
  float4 f0 = *(const float4*)(x + i);
  float4 f1 = *(const float4*)(x + i + 4);
  short8 r;
  r[0] = f2bbits(f0.x); r[1] = f2bbits(f0.y); r[2] = f2bbits(f0.z); r[3] = f2bbits(f0.w);
  r[4] = f2bbits(f1.x); r[5] = f2bbits(f1.y); r[6] = f2bbits(f1.z); r[7] = f2bbits(f1.w);
  *(short8*)(xb + i) = r;
}

// -------- W (1024 x cols, row-major fp32) -> dst[n][k] bf16 (transposed) --------
__global__ __launch_bounds__(256) void transpose_w(const float* __restrict__ src,
                                                   bf16* __restrict__ dst, int cols) {
  __shared__ float tile[32][33];
  int n0 = blockIdx.x * 32, k0 = blockIdx.y * 32;
  int tx = threadIdx.x & 31, ty = threadIdx.x >> 5;
#pragma unroll
  for (int i = 0; i < 32; i += 8) {
    int kk = k0 + ty + i, nn = n0 + tx;
    tile[ty + i][tx] = (nn < cols) ? src[(size_t)kk * cols + nn] : 0.0f;
  }
  __syncthreads();
#pragma unroll
  for (int i = 0; i < 32; i += 8) {
    int nn = n0 + ty + i, kk = k0 + tx;
    if (nn < cols) dst[(size_t)nn * 1024 + kk] = __float2bfloat16(tile[tx][ty + i]);
  }
}

// =====================================================================
// 256x256-tile bf16 MFMA GEMM, 8-wave (2Mx4N), BK=64, 8-phase schedule.
// v6 == the verified v2 loop (274 us, best measured), with q/k stored
// as bf16 in the mode-0 epilogue. T2 XOR-swizzle LDS, T3+T4 counted
// vmcnt, T5 setprio, T1 XCD-bijective block swizzle. LDS 128 KiB dyn.
// mode 0: projection epilogue, N=3072 (512 q | 512 k | 1024 v | 1024 g).
// mode 1: fp32 out, N=1024.
// =====================================================================
#define BARR __builtin_amdgcn_s_barrier()
#define WAITV(n) asm volatile("s_waitcnt vmcnt(" #n ")" ::: "memory")

// LDS map (shorts): A: buf*16384 + half*8192 ; B: 32768 + buf*16384 + half*8192
// Swizzle: 16B-granule p_phys = p_logical ^ (physrow & 7).
#define STA(buf, h, tau) do { \
  gload_lds16(pA + (size_t)(h) * K64 + (size_t)(tau) * 64, \
              &lds[(buf) * 16384 + (h) * 8192 + w * 512]); \
  gload_lds16(pA + K128 + (size_t)(h) * K64 + (size_t)(tau) * 64, \
              &lds[(buf) * 16384 + (h) * 8192 + 4096 + w * 512]); \
} while (0)

#define STB(buf, h, tau) do { \
  gload_lds16(pB + (size_t)(h) * K32 + (size_t)(tau) * 64, \
              &lds[32768 + (buf) * 16384 + (h) * 8192 + w * 512]); \
  gload_lds16(pB + K128 + (size_t)(h) * K32 + (size_t)(tau) * 64, \
              &lds[32768 + (buf) * 16384 + (h) * 8192 + 4096 + w * 512]); \
} while (0)

#define LDA(mh, buf) do { \
  _Pragma("unroll") \
  for (int mp = 0; mp < 4; ++mp) { \
    const short* p_ = &lds[(buf) * 16384 + (mh) * 8192 + aRow + mp * 1024]; \
    a[mp][0] = *(const short8*)(p_ + g0); \
    a[mp][1] = *(const short8*)(p_ + g1); \
  } \
} while (0)

#define LDB(nh, buf, d0, d1) do { \
  const short* p_ = &lds[(buf) * 16384 + (nh) * 8192 + bRow]; \
  d0[0] = *(const short8*)(p_ + g0); \
  d0[1] = *(const short8*)(p_ + g1); \
  d1[0] = *(const short8*)(p_ + 1024 + g0); \
  d1[1] = *(const short8*)(p_ + 1024 + g1); \
} while (0)

#define MQ(MB, NB, d0, d1) do { \
  __builtin_amdgcn_s_setprio(1); \
  _Pragma("unroll") \
  for (int mp = 0; mp < 4; ++mp) { \
    acc[(MB) + mp][(NB)] = __builtin_amdgcn_mfma_f32_16x16x32_bf16(a[mp][0], d0[0], acc[(MB) + mp][(NB)], 0, 0, 0); \
    acc[(MB) + mp][(NB)] = __builtin_amdgcn_mfma_f32_16x16x32_bf16(a[mp][1], d0[1], acc[(MB) + mp][(NB)], 0, 0, 0); \
    acc[(MB) + mp][(NB) + 1] = __builtin_amdgcn_mfma_f32_16x16x32_bf16(a[mp][0], d1[0], acc[(MB) + mp][(NB) + 1], 0, 0, 0); \
    acc[(MB) + mp][(NB) + 1] = __builtin_amdgcn_mfma_f32_16x16x32_bf16(a[mp][1], d1[1], acc[(MB) + mp][(NB) + 1], 0, 0, 0); \
  } \
  __builtin_amdgcn_s_setprio(0); \
} while (0)

__global__ __launch_bounds__(512, 2) void gemm256(
    const bf16* __restrict__ A, const bf16* __restrict__ Bt, const int K,
    const int nTN, const int mode,
    bf16* __restrict__ oq, bf16* __restrict__ okk, bf16* __restrict__ ov,
    bf16* __restrict__ ogg, float* __restrict__ oo) {
  extern __shared__ __align__(16) short lds[];
  const int tid = threadIdx.x;
  const int w = tid >> 6, lane = tid & 63;
  const int wr = w >> 2, wc = w & 3;               // 2M x 4N waves
  const int l15 = lane & 15, lq = lane >> 4;
  const int e7 = lane & 7, l3 = lane >> 3;
  const int gAp = (lane & 7) ^ l3;                 // staging: inverse-swizzled src granule

  // T1: bijective XCD swizzle (grid % 8 == 0), n-tile fastest for A reuse.
  const int cpx = (int)gridDim.x >> 3;
  const int bid = blockIdx.x;
  const int swz = (bid & 7) * cpx + (bid >> 3);
  const int mt = swz / nTN, nt = swz - mt * nTN;
  const int m0 = mt << 8, n0 = nt << 8;

  const size_t K64 = (size_t)K * 64, K128 = (size_t)K * 128, K32 = (size_t)K * 32;
  const bf16* pA = A + (size_t)(m0 + w * 8 + l3) * K + gAp * 8;
  const bf16* pB = Bt + (size_t)(n0 + (w >> 2) * 64 + (w & 3) * 8 + l3) * K + gAp * 8;

  const int g0 = ((lq ^ e7) & 7) * 8;              // kk=0 swizzled granule (shorts)
  const int g1 = (((lq + 4) ^ e7) & 7) * 8;        // kk=1
  const int aRow = (wr * 64 + l15) * 64;
  const int bRow = 32768 + (wc * 32 + l15) * 64;

  floatx4 acc[8][4] = {};
  short8 a[4][2], bb0[2], bb1[2], bb2[2], bb3[2];

  // Prologue: tile0 fully (buf0), tile1 A-h0 + B-h1 (buf1). vmcnt(4) leaves
  // only the last 2 half-tiles (tile1's) in flight.
  STA(0, 0, 0); STB(0, 0, 0); STB(0, 1, 0); STA(0, 1, 0);
  STA(1, 0, 1); STB(1, 1, 1);
  WAITV(4);
  BARR;

  const int nIter = K >> 7;  // 2 K-tiles (BK=64) per iteration
  for (int t = 0; t < nIter; ++t) {
    const bool nl = (t < nIter - 1);
    const int t1 = 2 * t + 1, t2 = 2 * t + 2, t3 = 2 * t + 3;
    // ---- ph1: quad(Mh0,Nh0) on buf0 ----
    LDA(0, 0); LDB(0, 0, bb0, bb1);
    STA(1, 1, t1);
    BARR; MQ(0, 0, bb0, bb1); BARR;
    // ---- ph2: quad(Mh0,Nh1) ----
    LDB(1, 0, bb2, bb3);
    STB(1, 0, t1);
    BARR; MQ(0, 2, bb2, bb3); BARR;
    // ---- ph3: quad(Mh1,Nh1) ----
    LDA(1, 0);
    if (nl) STA(0, 0, t2);
    BARR; MQ(4, 2, bb2, bb3); BARR;
    // ---- ph4: quad(Mh1,Nh0) ; counted vmcnt ----
    LDB(0, 0, bb0, bb1);
    if (nl) STB(0, 1, t2);
    BARR; MQ(4, 0, bb0, bb1);
    if (nl) { WAITV(4); } else { WAITV(0); }
    BARR;
    // ---- ph5: quad(Mh0,Nh0) on buf1 ----
    LDA(0, 1); LDB(0, 1, bb0, bb1);
    if (nl) STA(0, 1, t2);
    BARR; MQ(0, 0, bb0, bb1); BARR;
    // ---- ph6 ----
    LDB(1, 1, bb2, bb3);
    if (nl) STB(0, 0, t2);
    BARR; MQ(0, 2, bb2, bb3); BARR;
    // ---- ph7 ----
    LDA(1, 1);
    if (nl) STA(1, 0, t3);
    BARR; MQ(4, 2, bb2, bb3); BARR;
    // ---- ph8 ----
    LDB(0, 1, bb0, bb1);
    if (nl) STB(1, 1, t3);
    BARR; MQ(4, 0, bb0, bb1);
    if (nl) { WAITV(4); }
    BARR;
  }

  // Epilogue: C row = m0 + wr*128 + m*16 + lq*4 + r ; col = n0 + wc*64 + n*16 + l15
  const int rq = lq * 4;
#pragma unroll
  for (int m = 0; m < 8; ++m) {
#pragma unroll
    for (int n = 0; n < 4; ++n) {
      const int col = n0 + wc * 64 + n * 16 + l15;
#pragma unroll
      for (int r = 0; r < 4; ++r) {
        const size_t row = (size_t)(m0 + wr * 128 + m * 16 + rq + r);
        const float val = acc[m][n][r];
        if (mode == 1) {
          oo[row * 1024 + col] = val;
        } else if (col < 512) {
          oq[row * 512 + col] = __float2bfloat16(val * 0.08838834764831845f);
        } else if (col < 1024) {
          okk[row * 512 + (col - 512)] = __float2bfloat16(val);
        } else if (col < 2048) {
          ov[row * 1024 + (col - 1024)] = __float2bfloat16(val);
        } else {
          ogg[row * 1024 + (col - 2048)] = __float2bfloat16(val);
        }
      }
    }
  }
}

// ------------- gk = log_sigmoid((x @ w1) @ w2 + b2) / 16, log-space out -------------
// 4 rows per block; w1/w2 slices held in registers (fully static indexing).
__global__ __launch_bounds__(256) void gate_decay2(const float* __restrict__ x,
                                                   const float* __restrict__ w1,
                                                   const float* __restrict__ w2,
                                                   const float* __restrict__ b2,
                                                   float* __restrict__ gkout) {
  __shared__ float sp[256];
  __shared__ float sz[16];
  const int m0 = blockIdx.x * 4, tid = threadIdx.x;
  const int j = tid & 15, dpart = tid >> 4;
  float w1r[64];
#pragma unroll
  for (int e = 0; e < 64; ++e) w1r[e] = w1[(dpart * 64 + e) * 16 + j];
  float w2r[32];
#pragma unroll
  for (int jj = 0; jj < 16; ++jj) {
    w2r[jj] = w2[jj * 512 + tid];
    w2r[16 + jj] = w2[jj * 512 + tid + 256];
  }
  const float b2a = b2[tid], b2b = b2[tid + 256];
  for (int r = 0; r < 4; ++r) {
    const int m = m0 + r;
    const float* xr = x + (size_t)m * 1024 + dpart * 64;
    float acc = 0.f;
#pragma unroll
    for (int e = 0; e < 64; ++e) acc = fmaf(xr[e], w1r[e], acc);
    sp[tid] = acc;
    __syncthreads();
    if (tid < 16) {
      float s = 0.f;
#pragma unroll
      for (int p = 0; p < 16; ++p) s += sp[p * 16 + tid];
      sz[tid] = s;
    }
    __syncthreads();
    float t = b2a;
#pragma unroll
    for (int jj = 0; jj < 16; ++jj) t = fmaf(sz[jj], w2r[jj], t);
    const float ls = fminf(t, 0.f) - log1pf(__expf(-fabsf(t)));
    gkout[(size_t)m * 512 + tid] = ls * 0.0625f;
    float t2 = b2b;
#pragma unroll
    for (int jj = 0; jj < 16; ++jj) t2 = fmaf(sz[jj], w2r[16 + jj], t2);
    const float ls2 = fminf(t2, 0.f) - log1pf(__expf(-fabsf(t2)));
    gkout[(size_t)m * 512 + tid + 256] = ls2 * 0.0625f;
    if (r < 3) __syncthreads();
  }
}

// ------------- chunk prep: b=cumsum(gk); Qt=q*e^b, Kt=k*e^-b, Dtot=e^Btot -------------
// v2: q/k inputs now bf16 (halved read traffic).
__global__ __launch_bounds__(128) void chunk_prep(
    const bf16* __restrict__ q, const bf16* __restrict__ k,
    const float* __restrict__ gk, bf16* __restrict__ qt,
    bf16* __restrict__ kt, float* __restrict__ dtot) {
  const int cid = blockIdx.x;
  const int c = cid & 63, h = (cid >> 6) & 3, b = cid >> 8;
  const int d = threadIdx.x;
  const size_t rowbase = ((size_t)(b * 4096 + c * 64)) * 512 + h * 128 + d;
  const size_t obase = (size_t)cid * 8192 + d;
  float bsum = 0.f;
  for (int i = 0; i < 64; ++i) {
    const size_t src = rowbase + (size_t)i * 512;
    bsum += gk[src];
    qt[obase + (size_t)i * 128] = __float2bfloat16(__bfloat162float(q[src]) * __expf(bsum));
    kt[obase + (size_t)i * 128] = __float2bfloat16(__bfloat162float(k[src]) * __expf(-bsum));
  }
  dtot[cid * 128 + d] = __expf(bsum);
}

// ------------- chunk intra: A=tril(Qt@Kt^T); o_intra=A@V; U^T=V^T@(Kt*Dtot) -------------
__global__ __launch_bounds__(256) void chunk_intra(
    const bf16* __restrict__ qt, const bf16* __restrict__ kt,
    const float* __restrict__ dtot, const bf16* __restrict__ v,
    bf16* __restrict__ oi, bf16* __restrict__ ut) {
  __shared__ __align__(16) short lA[64 * 72];
  __shared__ __align__(16) short stg[27648];
  short* sQ = stg;               // 64 x 136
  short* sK = stg + 8704;        // 64 x 136
  short* sVT = stg;              // 256 x 72
  short* sKhT = stg + 18432;     // 128 x 72
  const int cid = blockIdx.x;
  const int c = cid & 63, h = (cid >> 6) & 3, b = cid >> 8;
  const int tid = threadIdx.x, wv = tid >> 6, lane = tid & 63;
  const int l15 = lane & 15, q8 = (lane >> 4) * 8, rq = (lane >> 4) * 4;

  {
    const int row = tid >> 2, seg = (tid & 3) * 32;
    const size_t src = (size_t)cid * 8192 + row * 128 + seg;
    const short8* qs = (const short8*)(qt + src);
    const short8* ks = (const short8*)(kt + src);
    short8* qd = (short8*)&sQ[row * 136 + seg];
    short8* kd = (short8*)&sK[row * 136 + seg];
#pragma unroll
    for (int t = 0; t < 4; ++t) { qd[t] = qs[t]; kd[t] = ks[t]; }
  }
  __syncthreads();
  {
    short8 af[4];
#pragma unroll
    for (int kf = 0; kf < 4; ++kf)
      af[kf] = *(const short8*)&sQ[(wv * 16 + l15) * 136 + kf * 32 + q8];
#pragma unroll
    for (int nt = 0; nt < 4; ++nt) {
      floatx4 accA = {0.f, 0.f, 0.f, 0.f};
#pragma unroll
      for (int kf = 0; kf < 4; ++kf) {
        short8 bfr = *(const short8*)&sK[(nt * 16 + l15) * 136 + kf * 32 + q8];
        accA = __builtin_amdgcn_mfma_f32_16x16x32_bf16(af[kf], bfr, accA, 0, 0, 0);
      }
#pragma unroll
      for (int r = 0; r < 4; ++r) {
        const int i = wv * 16 + rq + r, jj = nt * 16 + l15;
        lA[i * 72 + jj] = f2bbits(jj <= i ? accA[r] : 0.f);
      }
    }
  }
  __syncthreads();
  {
#pragma unroll
    for (int e = 0; e < 8; ++e) {
      const int idx = tid + e * 256;
      const int jj = idx >> 5, n0 = (idx & 31) * 8;
      short8 vv = *(const short8*)(v + ((size_t)(b * 4096 + c * 64 + jj)) * 1024 + h * 256 + n0);
#pragma unroll
      for (int t = 0; t < 8; ++t) sVT[(n0 + t) * 72 + jj] = vv[t];
    }
#pragma unroll
    for (int e = 0; e < 4; ++e) {
      const int idx = tid + e * 256;
      const int jj = idx >> 4, d0 = (idx & 15) * 8;
      short8 kk = *(const short8*)(kt + (size_t)cid * 8192 + jj * 128 + d0);
#pragma unroll
      for (int t = 0; t < 8; ++t)
        sKhT[(d0 + t) * 72 + jj] = f2bbits(b2f(kk[t]) * dtot[cid * 128 + d0 + t]);
    }
  }
  __syncthreads();
  {
    short8 aA0 = *(const short8*)&lA[(wv * 16 + l15) * 72 + q8];
    short8 aA1 = *(const short8*)&lA[(wv * 16 + l15) * 72 + 32 + q8];
#pragma unroll
    for (int nt = 0; nt < 16; ++nt) {
      short8 b0 = *(const short8*)&sVT[(nt * 16 + l15) * 72 + q8];
      short8 b1 = *(const short8*)&sVT[(nt * 16 + l15) * 72 + 32 + q8];
      floatx4 acc = {0.f, 0.f, 0.f, 0.f};
      acc = __builtin_amdgcn_mfma_f32_16x16x32_bf16(aA0, b0, acc, 0, 0, 0);
      acc = __builtin_amdgcn_mfma_f32_16x16x32_bf16(aA1, b1, acc, 0, 0, 0);
#pragma unroll
      for (int r = 0; r < 4; ++r) {
        const int i = wv * 16 + rq + r;
        oi[(size_t)cid * 16384 + i * 256 + nt * 16 + l15] = __builtin_bit_cast(bf16, f2bbits(acc[r]));
      }
    }
  }
  {
    short8 aV[4][2];
#pragma unroll
    for (int mt = 0; mt < 4; ++mt) {
      aV[mt][0] = *(const short8*)&sVT[(wv * 64 + mt * 16 + l15) * 72 + q8];
      aV[mt][1] = *(const short8*)&sVT[(wv * 64 + mt * 16 + l15) * 72 + 32 + q8];
    }
#pragma unroll
    for (int nt = 0; nt < 8; ++nt) {
      short8 b0 = *(const short8*)&sKhT[(nt * 16 + l15) * 72 + q8];
      short8 b1 = *(const short8*)&sKhT[(nt * 16 + l15) * 72 + 32 + q8];
#pragma unroll
      for (int mt = 0; mt < 4; ++mt) {
        floatx4 acc = {0.f, 0.f, 0.f, 0.f};
        acc = __builtin_amdgcn_mfma_f32_16x16x32_bf16(aV[mt][0], b0, acc, 0, 0, 0);
        acc = __builtin_amdgcn_mfma_f32_16x16x32_bf16(aV[mt][1], b1, acc, 0, 0, 0);
#pragma unroll
        for (int r = 0; r < 4; ++r) {
          const int vr = wv * 64 + mt * 16 + rq + r;
          ut[(size_t)cid * 32768 + vr * 128 + nt * 16 + l15] = __builtin_bit_cast(bf16, f2bbits(acc[r]));
        }
      }
    }
  }
}

// ------------- state propagation, IN PLACE over ut -------------
// 512 blocks (2/CU), 8 fp32 states per thread for latency hiding.
__global__ __launch_bounds__(256) void state_prop(
    bf16* __restrict__ su,          // in: U^T per chunk; out: S_pre per chunk
    const float* __restrict__ dtot) {
  const int ng = blockIdx.x, h = blockIdx.y, b = blockIdx.z;
  const int tid = threadIdx.x;
  const int nrow = ng * 16 + (tid >> 4), kseg = (tid & 15) * 8;
  const int cid0 = (b * 4 + h) * 64;
  size_t a = (size_t)cid0 * 32768 + (size_t)nrow * 128 + kseg;
  float S[8];
#pragma unroll
  for (int e = 0; e < 8; ++e) S[e] = 0.f;
  short8 u0 = *(const short8*)(su + a);
  for (int c = 0; c < 64; ++c) {
    short8 un0;
    if (c < 63) un0 = *(const short8*)(su + a + 32768);
    const float4 d0 = *(const float4*)(dtot + (cid0 + c) * 128 + kseg);
    const float4 d1 = *(const float4*)(dtot + (cid0 + c) * 128 + kseg + 4);
    short8 s0;
#pragma unroll
    for (int e = 0; e < 8; ++e) s0[e] = f2bbits(S[e]);
    *(short8*)(su + a) = s0;       // write S_pre over consumed U
    const float dd[8] = {d0.x, d0.y, d0.z, d0.w, d1.x, d1.y, d1.z, d1.w};
#pragma unroll
    for (int e = 0; e < 8; ++e) S[e] = fmaf(dd[e], S[e], b2f(u0[e]));
    u0 = un0;
    a += 32768;
  }
}

// ------------- o_inter + norm_gate FUSED -------------
// opre = oi + Qt @ S_pre; then per-head RMSNorm * gnw * swish(g) -> og.
// Block = one chunk (64 rows) x one head (256 cols) == exact norm domain.
__global__ __launch_bounds__(256, 2) void o_inter_norm(
    const bf16* __restrict__ qt, const bf16* __restrict__ scb,
    const bf16* __restrict__ oi, const bf16* __restrict__ g,
    const float* __restrict__ gnw, bf16* __restrict__ og) {
  __shared__ __align__(16) short sQ[64 * 136];
  __shared__ float sp[64 * 4];
  const int cid = blockIdx.x;
  const int c = cid & 63, h = (cid >> 6) & 3, b = cid >> 8;
  const int tid = threadIdx.x, wv = tid >> 6, lane = tid & 63;
  const int l15 = lane & 15, q8 = (lane >> 4) * 8, rq = (lane >> 4) * 4;
  {
    const int row = tid >> 2, seg = (tid & 3) * 32;
    const short8* qs = (const short8*)(qt + (size_t)cid * 8192 + row * 128 + seg);
    short8* qd = (short8*)&sQ[row * 136 + seg];
#pragma unroll
    for (int t = 0; t < 4; ++t) qd[t] = qs[t];
  }
  __syncthreads();
  short8 af[4][4];
#pragma unroll
  for (int i = 0; i < 4; ++i)
#pragma unroll
    for (int kf = 0; kf < 4; ++kf)
      af[i][kf] = *(const short8*)&sQ[(i * 16 + l15) * 136 + kf * 32 + q8];
  floatx4 acc[4][4] = {};
#pragma unroll
  for (int j = 0; j < 4; ++j) {
#pragma unroll
    for (int kf = 0; kf < 4; ++kf) {
      short8 bfr = *(const short8*)(scb + (size_t)cid * 32768 +
                                    (size_t)(wv * 64 + j * 16 + l15) * 128 + kf * 32 + q8);
#pragma unroll
      for (int i = 0; i < 4; ++i)
        acc[i][j] = __builtin_amdgcn_mfma_f32_16x16x32_bf16(af[i][kf], bfr, acc[i][j], 0, 0, 0);
    }
  }
  // val = acc + oi; per-row sum of squares (row = i*16+rq+r, wave cols = wv*64+j*16+l15)
#pragma unroll
  for (int i = 0; i < 4; ++i) {
#pragma unroll
    for (int r = 0; r < 4; ++r) {
      const int row = i * 16 + rq + r;
      float p = 0.f;
#pragma unroll
      for (int j = 0; j < 4; ++j) {
        const int col = wv * 64 + j * 16 + l15;
        const float v = acc[i][j][r] +
            __bfloat162float(oi[(size_t)cid * 16384 + row * 256 + col]);
        acc[i][j][r] = v;
        p = fmaf(v, v, p);
      }
      p += __shfl_xor(p, 1); p += __shfl_xor(p, 2);
      p += __shfl_xor(p, 4); p += __shfl_xor(p, 8);
      if (l15 == 0) sp[row * 4 + wv] = p;
    }
  }
  __syncthreads();
  const size_t rowg0 = (size_t)(b * 4096 + c * 64);
#pragma unroll
  for (int i = 0; i < 4; ++i) {
#pragma unroll
    for (int r = 0; r < 4; ++r) {
      const int row = i * 16 + rq + r;
      const float ms = (sp[row * 4] + sp[row * 4 + 1] + sp[row * 4 + 2] + sp[row * 4 + 3]) *
                       (1.0f / 256.0f);
      const float sc = rsqrtf(ms + 1e-5f);
#pragma unroll
      for (int j = 0; j < 4; ++j) {
        const int col = wv * 64 + j * 16 + l15;
        const size_t gi = (rowg0 + row) * 1024 + h * 256 + col;
        const float gv = __bfloat162float(g[gi]);
        const float sw = gv * (1.0f / (1.0f + __expf(-gv)));
        og[gi] = __float2bfloat16(acc[i][j][r] * sc * gnw[col] * sw);
      }
    }
  }
}

extern "C" void kernel_launch(void* const* d_in, const int* in_sizes, int n_in,
                              void* d_out, int out_size, void* d_ws, size_t ws_size,
                              hipStream_t stream) {
  const float* x   = (const float*)d_in[0];
  const float* Wq  = (const float*)d_in[1];
  const float* Wk  = (const float*)d_in[2];
  const float* Wv  = (const float*)d_in[3];
  const float* gw1 = (const float*)d_in[4];
  const float* gw2 = (const float*)d_in[5];
  const float* gb2 = (const float*)d_in[6];
  const float* Wg  = (const float*)d_in[7];
  const float* gnw = (const float*)d_in[8];
  const float* Wo  = (const float*)d_in[9];
  float* out = (float*)d_out;

  static bool attr_set = false;
  if (!attr_set) {
    hipFuncSetAttribute(reinterpret_cast<const void*>(gemm256),
                        hipFuncAttributeMaxDynamicSharedMemorySize, 131072);
    attr_set = true;
  }

  // carve (393 MiB); scb == utb (in-place state_prop); q/k now bf16.
  const size_t Mi = 1048576;
  uint8_t* w = (uint8_t*)d_ws;
  bf16*  wallT = (bf16*)(w);
  bf16*  woT   = (bf16*)(w + 6 * Mi);
  float* dtot  = (float*)(w + 8 * Mi);
  bf16*  xb    = (bf16*)(w + 9 * Mi);
  bf16*  qt    = (bf16*)(w + 9 * Mi);
  bf16*  ktb   = (bf16*)(w + 41 * Mi);
  float* qbF   = (float*)(w + 73 * Mi);   // (unused; kept for layout clarity)
  bf16*  qb    = (bf16*)(w + 73 * Mi);
  bf16*  kb    = (bf16*)(w + 137 * Mi);
  bf16*  utb   = (bf16*)(w + 73 * Mi);    // U^T then S_pre (in place, after qb/kb dead)
  float* gkb   = (float*)(w + 201 * Mi);
  bf16*  oib   = (bf16*)(w + 201 * Mi);
  bf16*  vb    = (bf16*)(w + 265 * Mi);
  bf16*  ogat  = (bf16*)(w + 265 * Mi);   // og written after vb consumed
  bf16*  gb    = (bf16*)(w + 329 * Mi);
  (void)qbF;

  convert_x<<<dim3(16384), 256, 0, stream>>>(x, xb);
  transpose_w<<<dim3(16, 32), 256, 0, stream>>>(Wq, wallT, 512);
  transpose_w<<<dim3(16, 32), 256, 0, stream>>>(Wk, wallT + (size_t)512 * 1024, 512);
  transpose_w<<<dim3(32, 32), 256, 0, stream>>>(Wv, wallT + (size_t)1024 * 1024, 1024);
  transpose_w<<<dim3(32, 32), 256, 0, stream>>>(Wg, wallT + (size_t)2048 * 1024, 1024);
  transpose_w<<<dim3(32, 32), 256, 0, stream>>>(Wo, woT, 1024);
  gemm256<<<dim3(1536), 512, 131072, stream>>>(xb, wallT, 1024, 12, 0, qb, kb, vb, gb, nullptr);
  gate_decay2<<<dim3(8192), 256, 0, stream>>>(x, gw1, gw2, gb2, gkb);
  chunk_prep<<<dim3(2048), 128, 0, stream>>>(qb, kb, gkb, qt, ktb, dtot);
  chunk_intra<<<dim3(2048), 256, 0, stream>>>(qt, ktb, dtot, vb, oib, utb);
  state_prop<<<dim3(16, 4, 8), 256, 0, stream>>>(utb, dtot);
  o_inter_norm<<<dim3(2048), 256, 0, stream>>>(qt, utb, oib, gb, gnw, ogat);
  gemm256<<<dim3(512), 512, 131072, stream>>>(ogat, woT, 1024, 4, 1, nullptr, nullptr, nullptr, nullptr, out);
}